// Round 1
// baseline (3555.544 us; speedup 1.0000x reference)
//
#include <hip/hip_runtime.h>
#include <stdint.h>

#define ROT(x, r) __builtin_rotateleft32((uint32_t)(x), (r))

// Threefry-2x32, 20 rounds (JAX jax/_src/prng.py threefry2x32)
#define TF_G1(x0, x1) \
  x0 += x1; x1 = ROT(x1, 13); x1 ^= x0; \
  x0 += x1; x1 = ROT(x1, 15); x1 ^= x0; \
  x0 += x1; x1 = ROT(x1, 26); x1 ^= x0; \
  x0 += x1; x1 = ROT(x1, 6);  x1 ^= x0;

#define TF_G2(x0, x1) \
  x0 += x1; x1 = ROT(x1, 17); x1 ^= x0; \
  x0 += x1; x1 = ROT(x1, 29); x1 ^= x0; \
  x0 += x1; x1 = ROT(x1, 16); x1 ^= x0; \
  x0 += x1; x1 = ROT(x1, 24); x1 ^= x0;

__device__ __forceinline__ void threefry_full(uint32_t k0, uint32_t k1,
                                              uint32_t c0, uint32_t c1,
                                              uint32_t& o0, uint32_t& o1) {
  uint32_t ks2 = k0 ^ k1 ^ 0x1BD11BDAu;
  uint32_t x0 = c0 + k0, x1 = c1 + k1;
  TF_G1(x0, x1); x0 += k1;  x1 += ks2 + 1u;
  TF_G2(x0, x1); x0 += ks2; x1 += k0 + 2u;
  TF_G1(x0, x1); x0 += k0;  x1 += k1 + 3u;
  TF_G2(x0, x1); x0 += k1;  x1 += ks2 + 4u;
  TF_G1(x0, x1); x0 += ks2; x1 += k0 + 5u;
  o0 = x0; o1 = x1;
}

// partitionable-mode random bits for 32-bit draws: counts = (hi=0, lo=cnt),
// bits = out0 ^ out1
__device__ __forceinline__ uint32_t tf_bits(uint32_t k0, uint32_t k1, uint32_t ks2,
                                            uint32_t cnt) {
  uint32_t x0 = k0;        // 0 + ks0
  uint32_t x1 = cnt + k1;  // cnt + ks1
  TF_G1(x0, x1); x0 += k1;  x1 += ks2 + 1u;
  TF_G2(x0, x1); x0 += ks2; x1 += k0 + 2u;
  TF_G1(x0, x1); x0 += k0;  x1 += k1 + 3u;
  TF_G2(x0, x1); x0 += k1;  x1 += ks2 + 4u;
  TF_G1(x0, x1); x0 += ks2; x1 += k0 + 5u;
  return x0 ^ x1;
}

// 16384 rows, 784 features, 10 outputs, 100 timesteps
// block: 256 threads = 8 rows x 32 lanes
__global__ __launch_bounds__(256, 4)
void snn_lif_kernel(const float* __restrict__ x, const float* __restrict__ W,
                    float* __restrict__ out) {
  // Wp[jj][q][jl][4]: q-th float4 of W[:, j=jl+32*jj]  (o = 4q+c; pads = 0)
  __shared__ __align__(16) float Wp[25 * 3 * 32 * 4];
  __shared__ uint32_t keys[100][2];

  const int tid = threadIdx.x;

  for (int s = tid; s < 25 * 3 * 32 * 4; s += 256) {
    int c = s & 3;
    int jl = (s >> 2) & 31;
    int rest = s >> 7;          // 0..74
    int q = rest % 3;
    int jj = rest / 3;
    int o = q * 4 + c;
    int j = jl + 32 * jj;
    float w = 0.0f;
    if (o < 10 && j < 784) w = W[o * 784 + j];
    Wp[s] = w;
  }
  if (tid < 100) {
    // fold-like split of root key (0,42): key_t = threefry((0,42),(0,t))
    uint32_t o0, o1;
    threefry_full(0u, 42u, 0u, (uint32_t)tid, o0, o1);
    keys[tid][0] = o0;
    keys[tid][1] = o1;
  }
  __syncthreads();

  const int row = blockIdx.x * 8 + (tid >> 5);
  const int jl = tid & 31;
  const float* xrow = x + (size_t)row * 784;
  const uint32_t cntbase = (uint32_t)row * 784u + (uint32_t)jl;

  float v[10], acc[10];
#pragma unroll
  for (int o = 0; o < 10; ++o) { v[o] = 0.0f; acc[o] = 0.0f; }

  for (int t = 0; t < 100; ++t) {
    uint32_t k0 = __builtin_amdgcn_readfirstlane(keys[t][0]);
    uint32_t k1 = __builtin_amdgcn_readfirstlane(keys[t][1]);
    uint32_t ks2 = k0 ^ k1 ^ 0x1BD11BDAu;

    float I[10];
#pragma unroll
    for (int o = 0; o < 10; ++o) I[o] = 0.0f;

#pragma unroll 5
    for (int jj = 0; jj < 25; ++jj) {
      int j = jl + (jj << 5);
      if (j < 784) {
        uint32_t bits = tf_bits(k0, k1, ks2, cntbase + (uint32_t)(jj << 5));
        float fm = (float)(bits >> 9);          // exact integer in [0,2^23)
        float xs = xrow[j] * 8388608.0f;        // x * 2^23, exact
        float s = (fm < xs) ? 1.0f : 0.0f;      // == (u < x), bit-exact

        const float4* wq = (const float4*)&Wp[((jj * 3) * 32 + jl) * 4];
        float4 wa = wq[0];
        float4 wb = wq[32];
        float4 wc = wq[64];
        I[0] += s * wa.x; I[1] += s * wa.y; I[2] += s * wa.z; I[3] += s * wa.w;
        I[4] += s * wb.x; I[5] += s * wb.y; I[6] += s * wb.z; I[7] += s * wb.w;
        I[8] += s * wc.x; I[9] += s * wc.y;
      }
    }

    // reduce partial I across the row's 32 lanes
#pragma unroll
    for (int o = 0; o < 10; ++o) {
      float r = I[o];
      r += __shfl_xor(r, 1, 32);
      r += __shfl_xor(r, 2, 32);
      r += __shfl_xor(r, 4, 32);
      r += __shfl_xor(r, 8, 32);
      r += __shfl_xor(r, 16, 32);
      I[o] = r;
    }

    // LIF update (replicated across the 32 lanes of the row)
#pragma unroll
    for (int o = 0; o < 10; ++o) {
      float vv = v[o] + (I[o] - v[o]) * 0.5f;   // v += (I - v)/tau, tau=2 (exact)
      float s = (vv >= 1.0f) ? 1.0f : 0.0f;     // == (v - 1.0 >= 0)
      acc[o] += s;
      v[o] = (1.0f - s) * vv;                   // hard reset (exact: 0 or vv)
    }
  }

  if (jl == 0) {
#pragma unroll
    for (int o = 0; o < 10; ++o)
      out[(size_t)row * 10 + o] = acc[o] / 100.0f;
  }
}

extern "C" void kernel_launch(void* const* d_in, const int* in_sizes, int n_in,
                              void* d_out, int out_size, void* d_ws, size_t ws_size,
                              hipStream_t stream) {
  const float* x = (const float*)d_in[0];   // [16384,1,28,28] fp32
  const float* W = (const float*)d_in[1];   // [10,784] fp32
  float* out = (float*)d_out;               // [16384,10] fp32
  hipLaunchKernelGGL(snn_lif_kernel, dim3(2048), dim3(256), 0, stream, x, W, out);
}